// Round 5
// baseline (383.010 us; speedup 1.0000x reference)
//
#include <hip/hip_runtime.h>

typedef unsigned short u16;
typedef unsigned int u32;
typedef float f32x4 __attribute__((ext_vector_type(4)));
typedef int i32x4 __attribute__((ext_vector_type(4)));
typedef __bf16 bf16x8 __attribute__((ext_vector_type(8)));
typedef short s16x8 __attribute__((ext_vector_type(8)));

#define CN0 655360
#define CN1 81920
#define CN2 8192

// ---------------- ws layout (bytes) ----------------
#define H0_OFF    0ull            // u16[81920*256] (l2normed layer0 out; later reused as m1)
#define T_OFF     41943040ull     // u16[81920*256] (hidden pre-bn t)
#define H2_OFF    83886080ull     // u16[8192*256]  (relu(bnh(t)) head rows)
#define ZZ_OFF    88080384ull     // f32[8192*256]  (pre-bnl latent)
#define WP0F_OFF  96468992ull     // u16[128*128] frag
#define WC0F_OFF  96501760ull     // u16[256*256] frag [Wself0;Wneigh0]
#define WHF_OFF   96632832ull     // u16[256*256] frag
#define WP1F_OFF  96763904ull     // u16[256*256] frag
#define WC1F_OFF  96894976ull     // u16[512*256] frag [Wself1;Wneigh1]
#define WLATF_OFF 97157120ull     // u16[256*256] frag
#define STAT_OFF  97288192ull     // f32[6*256]: bn0 sum/sumsq, bnh, bnl
#define M_OFF     97294336ull     // u16[655360*128] dense m-table (bf16)
#define M_BYTES   167772160ull

__device__ inline u16 f2bf(float f) {
  u32 u = __builtin_bit_cast(u32, f);
  return (u16)((u + 0x7fffu + ((u >> 16) & 1u)) >> 16);  // RNE
}
__device__ inline float bf2f(u16 s) {
  return __builtin_bit_cast(float, (u32)s << 16);
}
// 8×f32 -> packed bf16x8 (compiler emits v_cvt_pk_bf16_f32)
__device__ inline i32x4 cvt8(f32x4 a, f32x4 b) {
  union { bf16x8 v; i32x4 q; } u;
  #pragma unroll
  for (int j = 0; j < 4; ++j) { u.v[j] = (__bf16)a[j]; u.v[4 + j] = (__bf16)b[j]; }
  return u.q;
}

// MFMA shim: gfx950 builtin takes either v8bf16 or v8i16 depending on
// toolchain; SFINAE picks whichever compiles.
template <typename V>
__device__ inline auto mfma_sel(V a, V b, f32x4 c, int)
    -> decltype(__builtin_amdgcn_mfma_f32_16x16x32_bf16(a, b, c, 0, 0, 0)) {
  return __builtin_amdgcn_mfma_f32_16x16x32_bf16(a, b, c, 0, 0, 0);
}
template <typename V>
__device__ inline f32x4 mfma_sel(V a, V b, f32x4 c, long) {
  return __builtin_amdgcn_mfma_f32_16x16x32_bf16(
      __builtin_bit_cast(s16x8, a), __builtin_bit_cast(s16x8, b), c, 0, 0, 0);
}
__device__ inline f32x4 MFMA(i32x4 a, i32x4 b, f32x4 c) {
  return mfma_sel(__builtin_bit_cast(bf16x8, a), __builtin_bit_cast(bf16x8, b), c, 0);
}

// ---------------- weight prep: bf16 + MFMA-B fragment order ----------------
// storage [kt][nt][lane][j]; value = B[kt*32 + 8*(lane>>4) + j][nt*16 + (lane&15)]
__device__ void fragify(const float* W0, const float* W1, int Khalf, int N,
                        u16* dst, int tid, int nthr) {
  int K = W1 ? 2 * Khalf : Khalf;
  int ntile = N >> 4;
  int total = (K >> 5) * ntile * 512;
  for (int i = tid; i < total; i += nthr) {
    int j = i & 7;
    int lane = (i >> 3) & 63;
    int nt = (i >> 9) % ntile;
    int kt = i / (512 * ntile);
    int k = kt * 32 + ((lane >> 4) << 3) + j;
    int n = nt * 16 + (lane & 15);
    float v = (k < Khalf) ? W0[k * N + n] : W1[(k - Khalf) * N + n];
    dst[i] = f2bf(v);
  }
}

__global__ void kprep(const float* Wp0, const float* Ws0, const float* Wn0,
                      const float* Wh, const float* Wp1, const float* Ws1,
                      const float* Wn1, const float* Wlat,
                      u16* wp0f, u16* wc0f, u16* whf, u16* wp1f, u16* wc1f,
                      u16* wlatf, float* stat) {
  int tid = blockIdx.x * blockDim.x + threadIdx.x;
  int nthr = gridDim.x * blockDim.x;
  if (blockIdx.x == 0) {
    #pragma unroll
    for (int i = 0; i < 6; ++i) stat[threadIdx.x + i * 256] = 0.0f;
  }
  fragify(Wp0, nullptr, 128, 128, wp0f, tid, nthr);
  fragify(Ws0, Wn0, 128, 256, wc0f, tid, nthr);
  fragify(Wh, nullptr, 256, 256, whf, tid, nthr);
  fragify(Wp1, nullptr, 256, 256, wp1f, tid, nthr);
  fragify(Ws1, Wn1, 256, 256, wc1f, tid, nthr);
  fragify(Wlat, nullptr, 256, 256, wlatf, tid, nthr);
}

// ---------------- kM: dense M = relu(x @ Wp0 + bp0) bf16, all N0 rows ----
// Streaming BW-bound GEMM; 64 rows/block, wave handles 16 rows.
__global__ __launch_bounds__(256, 6)
void kM(const float* __restrict__ x, const u16* __restrict__ wp0f,
        const float* __restrict__ bp0, u16* __restrict__ Mt) {
  __shared__ __align__(16) u16 mst[64][132];   // +4 pad: conflict-light
  int tid = threadIdx.x, lane = tid & 63, w = tid >> 6;
  int r15 = lane & 15, g = lane >> 4;
  size_t row0 = (size_t)blockIdx.x * 64 + (size_t)w * 16;
  const float* rp = x + (row0 + (size_t)r15) * 128;
  i32x4 afr[4];
  #pragma unroll
  for (int kt = 0; kt < 4; ++kt) {
    f32x4 p0 = *(const f32x4*)(rp + kt * 32 + g * 8);
    f32x4 p1 = *(const f32x4*)(rp + kt * 32 + g * 8 + 4);
    afr[kt] = cvt8(p0, p1);
  }
  f32x4 acc[8] = {};
  #pragma unroll
  for (int kt = 0; kt < 4; ++kt) {
    #pragma unroll
    for (int nt = 0; nt < 8; ++nt) {
      i32x4 b = *(const i32x4*)(wp0f + (((kt * 8 + nt) * 64 + lane) << 3));
      acc[nt] = MFMA(afr[kt], b, acc[nt]);
    }
  }
  #pragma unroll
  for (int nt = 0; nt < 8; ++nt) {
    float bias = bp0[nt * 16 + r15];
    #pragma unroll
    for (int j = 0; j < 4; ++j)
      mst[w * 16 + g * 4 + j][nt * 16 + r15] = f2bf(fmaxf(acc[nt][j] + bias, 0.0f));
  }
  // per-wave transpose-readback (same wave wrote its own 16-row slice;
  // compiler inserts lgkmcnt wait) -> coalesced row-major global store
  int lr = lane >> 2, lc = lane & 3;
  u16* orow = Mt + (row0 + (size_t)lr) * 128 + lc * 32;
  const u16* srow = &mst[w * 16 + lr][lc * 32];
  #pragma unroll
  for (int c = 0; c < 4; ++c)
    *(i32x4*)(orow + c * 8) = *(const i32x4*)(srow + c * 8);
}

// ---------------- k1b: layer-0 pooling from M-table + concat GEMM ----------
// Gather-max over bf16 M rows (L3-resident, no MFMA dependency), then
// u=[x_dst|pooled] @ Wcat0, l2norm, bn0 stats, h0 store.
__global__ __launch_bounds__(256, 6)
void k1b(const u16* __restrict__ Mt, const float* __restrict__ x,
         const int* __restrict__ esrc, const u16* __restrict__ wc0f,
         const float* __restrict__ b0v, u16* __restrict__ h0,
         float* __restrict__ stat0) {
  __shared__ __align__(16) char lds[16896];  // u [32][256]bf16 @0; rowsum f32[32][4] @16384
  float* rsb = (float*)(lds + 16384);
  int tid = threadIdx.x, lane = tid & 63, w = tid >> 6;
  int r15 = lane & 15, g = lane >> 4;
  int d0 = blockIdx.x * 32;

  // ---- prefetch x_dst rows (independent; latency hides under gather)
  int i_ = tid >> 3, part_ = tid & 7;
  const float* xr_ = x + (size_t)(d0 + i_) * 128 + part_ * 16;
  f32x4 t0 = *(const f32x4*)(xr_ + 0);
  f32x4 t1 = *(const f32x4*)(xr_ + 4);
  f32x4 t2 = *(const f32x4*)(xr_ + 8);
  f32x4 t3 = *(const f32x4*)(xr_ + 12);

  // ---- gather-max: dst i = tid>>3, 16 cols per thread (part*16)
  {
    int i = tid >> 3, part = tid & 7;
    const int* ep = esrc + (d0 + i) * 8;
    union { i32x4 q; u16 h[8]; } mx0, mx1;
    mx0.q = i32x4{0, 0, 0, 0};   // m >= 0 (relu) -> u16 bit-max == value max
    mx1.q = i32x4{0, 0, 0, 0};
    #pragma unroll
    for (int e = 0; e < 8; ++e) {
      const u16* mr = Mt + (size_t)ep[e] * 128 + part * 16;
      union { i32x4 q; u16 h[8]; } a, b;
      a.q = *(const i32x4*)(mr);
      b.q = *(const i32x4*)(mr + 8);
      #pragma unroll
      for (int j = 0; j < 8; ++j) {
        mx0.h[j] = a.h[j] > mx0.h[j] ? a.h[j] : mx0.h[j];
        mx1.h[j] = b.h[j] > mx1.h[j] ? b.h[j] : mx1.h[j];
      }
    }
    u32 sw = (u32)((i & 7) << 4);
    *(i32x4*)(lds + (((u32)i * 512 + 256 + (u32)part * 32) ^ sw)) = mx0.q;
    *(i32x4*)(lds + (((u32)i * 512 + 256 + (u32)part * 32 + 16) ^ sw)) = mx1.q;
  }

  // ---- u[0:128] = x_dst (bf16, swizzled) from prefetched regs
  {
    u32 sw = (u32)((i_ & 7) << 4);
    *(i32x4*)(lds + (((u32)i_ * 512 + (u32)part_ * 32) ^ sw)) = cvt8(t0, t1);
    *(i32x4*)(lds + (((u32)i_ * 512 + (u32)part_ * 32 + 16) ^ sw)) = cvt8(t2, t3);
  }
  __syncthreads();

  // ---- GEMM: h0row = u @ Wcat0 + b0 (K=256)
  f32x4 acc2[4][2] = {};
  for (int kt = 0; kt < 8; ++kt) {
    u32 r0 = (u32)r15, r1 = (u32)(16 + r15);
    i32x4 a0 = *(const i32x4*)(lds + ((r0 * 512 + (u32)kt * 64 + (u32)g * 16) ^ ((r0 & 7) << 4)));
    i32x4 a1 = *(const i32x4*)(lds + ((r1 * 512 + (u32)kt * 64 + (u32)g * 16) ^ ((r1 & 7) << 4)));
    #pragma unroll
    for (int n4 = 0; n4 < 4; ++n4) {
      int nt = w * 4 + n4;
      i32x4 b = *(const i32x4*)(wc0f + (((size_t)(kt * 16 + nt) * 64 + lane) << 3));
      acc2[n4][0] = MFMA(a0, b, acc2[n4][0]);
      acc2[n4][1] = MFMA(a1, b, acc2[n4][1]);
    }
  }

  // ---- epilogue: bias, l2norm (register), bn0 stats, bf16 store
  float vn[4][2][4];
  #pragma unroll
  for (int n4 = 0; n4 < 4; ++n4) {
    float bv = b0v[(w * 4 + n4) * 16 + r15];
    #pragma unroll
    for (int rt = 0; rt < 2; ++rt)
      #pragma unroll
      for (int j = 0; j < 4; ++j) vn[n4][rt][j] = acc2[n4][rt][j] + bv;
  }
  #pragma unroll
  for (int rt = 0; rt < 2; ++rt)
    #pragma unroll
    for (int j = 0; j < 4; ++j) {
      float s = 0.0f;
      #pragma unroll
      for (int n4 = 0; n4 < 4; ++n4) s += vn[n4][rt][j] * vn[n4][rt][j];
      s += __shfl_xor(s, 1); s += __shfl_xor(s, 2);
      s += __shfl_xor(s, 4); s += __shfl_xor(s, 8);
      if (r15 == 0) rsb[(rt * 16 + g * 4 + j) * 4 + w] = s;
    }
  __syncthreads();   // rowsums ready; u-LDS now dead

  #pragma unroll
  for (int rt = 0; rt < 2; ++rt)
    #pragma unroll
    for (int j = 0; j < 4; ++j) {
      int r = rt * 16 + g * 4 + j;
      f32x4 q = *(const f32x4*)&rsb[r * 4];
      float rn = 1.0f / fmaxf(sqrtf(q[0] + q[1] + q[2] + q[3]), 1e-12f);
      #pragma unroll
      for (int n4 = 0; n4 < 4; ++n4) vn[n4][rt][j] *= rn;
    }
  #pragma unroll
  for (int n4 = 0; n4 < 4; ++n4) {
    int col = (w * 4 + n4) * 16 + r15;
    float s1 = 0.0f, s2 = 0.0f;
    #pragma unroll
    for (int rt = 0; rt < 2; ++rt)
      #pragma unroll
      for (int j = 0; j < 4; ++j) { float v = vn[n4][rt][j]; s1 += v; s2 += v * v; }
    s1 += __shfl_xor(s1, 16); s1 += __shfl_xor(s1, 32);
    s2 += __shfl_xor(s2, 16); s2 += __shfl_xor(s2, 32);
    if (g == 0) { atomicAdd(&stat0[col], s1); atomicAdd(&stat0[256 + col], s2); }
  }
  #pragma unroll
  for (int n4 = 0; n4 < 4; ++n4)
    #pragma unroll
    for (int rt = 0; rt < 2; ++rt)
      #pragma unroll
      for (int j = 0; j < 4; ++j)
        *(u16*)(lds + (u32)(rt * 16 + g * 4 + j) * 512 + (u32)((w * 4 + n4) * 16 + r15) * 2)
            = f2bf(vn[n4][rt][j]);
  __syncthreads();
  {
    int i = tid >> 3, c8 = tid & 7;
    const char* srcp = lds + i * 512 + c8 * 64;
    u16* dst = h0 + (size_t)(d0 + i) * 256 + c8 * 32;
    #pragma unroll
    for (int c = 0; c < 4; ++c)
      *(i32x4*)(dst + c * 8) = *(const i32x4*)(srcp + c * 16);
  }
}

// ---------------- K1 (fallback, ws too small): fused layer-0 SAGE ----------
__global__ __launch_bounds__(256, 4)
void k1_layer0(const float* __restrict__ x, const int* __restrict__ esrc,
               const u16* __restrict__ wp0f, const u16* __restrict__ wc0f,
               const float* __restrict__ bp0, const float* __restrict__ b0v,
               u16* __restrict__ h0, float* __restrict__ stat0) {
  __shared__ __align__(16) char lds[16896];
  float* rsb = (float*)(lds + 16384);
  int tid = threadIdx.x, lane = tid & 63, w = tid >> 6;
  int r15 = lane & 15, g = lane >> 4;
  int d0 = blockIdx.x * 32;
  int i_ = tid >> 3, part_ = tid & 7;
  const float* xr_ = x + (size_t)(d0 + i_) * 128 + part_ * 16;
  f32x4 t0 = *(const f32x4*)(xr_ + 0);
  f32x4 t1 = *(const f32x4*)(xr_ + 4);
  f32x4 t2 = *(const f32x4*)(xr_ + 8);
  f32x4 t3 = *(const f32x4*)(xr_ + 12);
  {
    int e0 = d0 * 8 + w * 64;
    const float* rp[4];
    #pragma unroll
    for (int rt = 0; rt < 4; ++rt)
      rp[rt] = x + (size_t)esrc[e0 + rt * 16 + r15] * 128;
    i32x4 afr[4][4];
    #pragma unroll
    for (int rt = 0; rt < 4; ++rt)
      #pragma unroll
      for (int kt = 0; kt < 4; ++kt) {
        f32x4 p0 = *(const f32x4*)(rp[rt] + kt * 32 + g * 8);
        f32x4 p1 = *(const f32x4*)(rp[rt] + kt * 32 + g * 8 + 4);
        afr[rt][kt] = cvt8(p0, p1);
      }
    for (int nt = 0; nt < 8; ++nt) {
      f32x4 acc[4] = {};
      #pragma unroll
      for (int kt = 0; kt < 4; ++kt) {
        i32x4 b = *(const i32x4*)(wp0f + (((kt * 8 + nt) * 64 + lane) << 3));
        #pragma unroll
        for (int rt = 0; rt < 4; ++rt) acc[rt] = MFMA(afr[rt][kt], b, acc[rt]);
      }
      float bias = bp0[nt * 16 + r15];
      #pragma unroll
      for (int rt = 0; rt < 4; ++rt) {
        float mx = fmaxf(fmaxf(acc[rt][0], acc[rt][1]), fmaxf(acc[rt][2], acc[rt][3]));
        mx = fmaxf(mx + bias, 0.0f);
        mx = fmaxf(mx, __shfl_xor(mx, 16));
        if ((g & 1) == 0) {
          u32 row = (u32)(w * 8 + rt * 2 + (g >> 1));
          u32 byte = (row * 512 + 256 + (u32)(nt * 16 + r15) * 2) ^ ((row & 7) << 4);
          *(u16*)(lds + byte) = f2bf(mx);
        }
      }
    }
  }
  {
    u32 sw = (u32)((i_ & 7) << 4);
    *(i32x4*)(lds + (((u32)i_ * 512 + (u32)part_ * 32) ^ sw)) = cvt8(t0, t1);
    *(i32x4*)(lds + (((u32)i_ * 512 + (u32)part_ * 32 + 16) ^ sw)) = cvt8(t2, t3);
  }
  __syncthreads();
  f32x4 acc2[4][2] = {};
  for (int kt = 0; kt < 8; ++kt) {
    u32 r0 = (u32)r15, r1 = (u32)(16 + r15);
    i32x4 a0 = *(const i32x4*)(lds + ((r0 * 512 + (u32)kt * 64 + (u32)g * 16) ^ ((r0 & 7) << 4)));
    i32x4 a1 = *(const i32x4*)(lds + ((r1 * 512 + (u32)kt * 64 + (u32)g * 16) ^ ((r1 & 7) << 4)));
    #pragma unroll
    for (int n4 = 0; n4 < 4; ++n4) {
      int nt = w * 4 + n4;
      i32x4 b = *(const i32x4*)(wc0f + (((size_t)(kt * 16 + nt) * 64 + lane) << 3));
      acc2[n4][0] = MFMA(a0, b, acc2[n4][0]);
      acc2[n4][1] = MFMA(a1, b, acc2[n4][1]);
    }
  }
  float vn[4][2][4];
  #pragma unroll
  for (int n4 = 0; n4 < 4; ++n4) {
    float bv = b0v[(w * 4 + n4) * 16 + r15];
    #pragma unroll
    for (int rt = 0; rt < 2; ++rt)
      #pragma unroll
      for (int j = 0; j < 4; ++j) vn[n4][rt][j] = acc2[n4][rt][j] + bv;
  }
  #pragma unroll
  for (int rt = 0; rt < 2; ++rt)
    #pragma unroll
    for (int j = 0; j < 4; ++j) {
      float s = 0.0f;
      #pragma unroll
      for (int n4 = 0; n4 < 4; ++n4) s += vn[n4][rt][j] * vn[n4][rt][j];
      s += __shfl_xor(s, 1); s += __shfl_xor(s, 2);
      s += __shfl_xor(s, 4); s += __shfl_xor(s, 8);
      if (r15 == 0) rsb[(rt * 16 + g * 4 + j) * 4 + w] = s;
    }
  __syncthreads();
  #pragma unroll
  for (int rt = 0; rt < 2; ++rt)
    #pragma unroll
    for (int j = 0; j < 4; ++j) {
      int r = rt * 16 + g * 4 + j;
      f32x4 q = *(const f32x4*)&rsb[r * 4];
      float rn = 1.0f / fmaxf(sqrtf(q[0] + q[1] + q[2] + q[3]), 1e-12f);
      #pragma unroll
      for (int n4 = 0; n4 < 4; ++n4) vn[n4][rt][j] *= rn;
    }
  #pragma unroll
  for (int n4 = 0; n4 < 4; ++n4) {
    int col = (w * 4 + n4) * 16 + r15;
    float s1 = 0.0f, s2 = 0.0f;
    #pragma unroll
    for (int rt = 0; rt < 2; ++rt)
      #pragma unroll
      for (int j = 0; j < 4; ++j) { float v = vn[n4][rt][j]; s1 += v; s2 += v * v; }
    s1 += __shfl_xor(s1, 16); s1 += __shfl_xor(s1, 32);
    s2 += __shfl_xor(s2, 16); s2 += __shfl_xor(s2, 32);
    if (g == 0) { atomicAdd(&stat0[col], s1); atomicAdd(&stat0[256 + col], s2); }
  }
  #pragma unroll
  for (int n4 = 0; n4 < 4; ++n4)
    #pragma unroll
    for (int rt = 0; rt < 2; ++rt)
      #pragma unroll
      for (int j = 0; j < 4; ++j)
        *(u16*)(lds + (u32)(rt * 16 + g * 4 + j) * 512 + (u32)((w * 4 + n4) * 16 + r15) * 2)
            = f2bf(vn[n4][rt][j]);
  __syncthreads();
  {
    int i = tid >> 3, c8 = tid & 7;
    const char* srcp = lds + i * 512 + c8 * 64;
    u16* dst = h0 + (size_t)(d0 + i) * 256 + c8 * 32;
    #pragma unroll
    for (int c = 0; c < 4; ++c)
      *(i32x4*)(dst + c * 8) = *(const i32x4*)(srcp + c * 16);
  }
}

// ---------------- gemm64: Out = [relu(bn(Ain))] @ Bf + bias ----------------
template <bool RELU_OUT, bool STATS, bool H2OUT>
__global__ __launch_bounds__(256, 4)
void gemm64(const u16* __restrict__ Ain, const float* __restrict__ statin,
            float inv_n, const float* __restrict__ gg, const float* __restrict__ bb,
            const u16* __restrict__ Bf, const float* __restrict__ bias,
            u16* __restrict__ Out, float* __restrict__ statout,
            u16* __restrict__ H2out) {
  __shared__ __align__(16) char lds[34816];  // A-stage/tb share [0,32768); scs @32768
  u16* tb = (u16*)lds;
  float* scs = (float*)(lds + 32768);
  int tid = threadIdx.x, lane = tid & 63, w = tid >> 6;
  int r15 = lane & 15, g = lane >> 4;
  int d0 = blockIdx.x * 64;
  {
    float mu = statin[tid] * inv_n;
    float var = statin[256 + tid] * inv_n - mu * mu;
    float sc = gg[tid] / sqrtf(var + 1e-5f);
    scs[tid] = sc;
    scs[256 + tid] = bb[tid] - mu * sc;
  }
  __syncthreads();
  {
    int i = tid >> 2, part = tid & 3;
    const u16* ar = Ain + (size_t)(d0 + i) * 256 + part * 64;
    u32 sw = (u32)((i & 7) << 4), rowb = (u32)i * 512;
    for (int cc = 0; cc < 8; ++cc) {
      union { i32x4 q; u16 h[8]; } in, out;
      in.q = *(const i32x4*)(ar + cc * 8);
      #pragma unroll
      for (int j = 0; j < 8; ++j) {
        int k = part * 64 + cc * 8 + j;
        float v = fmaxf(bf2f(in.h[j]) * scs[k] + scs[256 + k], 0.0f);
        out.h[j] = f2bf(v);
      }
      *(i32x4*)(lds + ((rowb + (u32)(part * 64 + cc * 8) * 2) ^ sw)) = out.q;
    }
  }
  __syncthreads();

  f32x4 acc[4][4] = {};
  for (int kt = 0; kt < 8; ++kt) {
    i32x4 a[4];
    #pragma unroll
    for (int rt = 0; rt < 4; ++rt) {
      u32 r = (u32)(rt * 16 + r15);
      a[rt] = *(const i32x4*)(lds + ((r * 512 + (u32)kt * 64 + (u32)g * 16) ^ ((r & 7) << 4)));
    }
    #pragma unroll
    for (int n4 = 0; n4 < 4; ++n4) {
      int nt = w * 4 + n4;
      i32x4 b = *(const i32x4*)(Bf + (((size_t)(kt * 16 + nt) * 64 + lane) << 3));
      #pragma unroll
      for (int rt = 0; rt < 4; ++rt) acc[n4][rt] = MFMA(a[rt], b, acc[n4][rt]);
    }
  }
  __syncthreads();

  if constexpr (H2OUT) {
    if (d0 < CN2) {
      int i = tid >> 2, part = tid & 3;
      u16* orow = H2out + (size_t)(d0 + i) * 256 + part * 64;
      u32 sw = (u32)((i & 7) << 4);
      #pragma unroll
      for (int cc = 0; cc < 8; ++cc)
        *(i32x4*)(orow + cc * 8) =
            *(const i32x4*)(lds + (((u32)i * 512 + (u32)(part * 64 + cc * 8) * 2) ^ sw));
    }
    __syncthreads();
  }

  #pragma unroll
  for (int n4 = 0; n4 < 4; ++n4) {
    int col = (w * 4 + n4) * 16 + r15;
    float bv = bias[col];
    #pragma unroll
    for (int rt = 0; rt < 4; ++rt)
      #pragma unroll
      for (int j = 0; j < 4; ++j) {
        float v = acc[n4][rt][j] + bv;
        if (RELU_OUT) v = fmaxf(v, 0.0f);
        tb[(rt * 16 + g * 4 + j) * 256 + col] = f2bf(v);
      }
  }
  __syncthreads();

  {
    int i = tid >> 2, part = tid & 3;
    u16* orow = Out + (size_t)(d0 + i) * 256 + part * 64;
    const u16* trow = tb + i * 256 + part * 64;
    #pragma unroll
    for (int cc = 0; cc < 8; ++cc)
      *(i32x4*)(orow + cc * 8) = *(const i32x4*)(trow + cc * 8);
  }
  if (STATS) {
    int c = tid; float s1 = 0.0f, s2 = 0.0f;
    for (int r = 0; r < 64; ++r) { float v = bf2f(tb[r * 256 + c]); s1 += v; s2 += v * v; }
    atomicAdd(&statout[c], s1); atomicAdd(&statout[256 + c], s2);
  }
}

// ---------------- K6: fused layer-1 (16 dst / block, 4 blocks/CU) ----------------
__global__ __launch_bounds__(256, 4)
void k6_layer1(const int* __restrict__ esrc1, const u16* __restrict__ m1,
               const u16* __restrict__ h2, const u16* __restrict__ wc1f,
               const u16* __restrict__ wlatf, const float* __restrict__ b1v,
               const float* __restrict__ blat, float* __restrict__ zz,
               float* __restrict__ statl) {
  __shared__ __align__(16) char lds[40960];
  float* zbuf = (float*)(lds + 16384);
  int tid = threadIdx.x, lane = tid & 63, w = tid >> 6;
  int r15 = lane & 15, g = lane >> 4;
  int d0 = blockIdx.x * 16;
  {
    int i = tid >> 4, part = tid & 15;
    u32 sw = (u32)((i & 7) << 4);
    const u16* hrow = h2 + (size_t)(d0 + i) * 256 + part * 16;
    i32x4 q0 = *(const i32x4*)(hrow);
    i32x4 q1 = *(const i32x4*)(hrow + 8);
    *(i32x4*)(lds + (((u32)i * 1024 + (u32)(part * 16) * 2) ^ sw)) = q0;
    *(i32x4*)(lds + (((u32)i * 1024 + (u32)(part * 16) * 2 + 16) ^ sw)) = q1;
    float mx[16];
    #pragma unroll
    for (int c = 0; c < 16; ++c) mx[c] = -1e30f;
    const int* ep = esrc1 + (d0 + i) * 10;
    #pragma unroll 2
    for (int e = 0; e < 10; ++e) {
      int src = ep[e];
      const u16* mrow = m1 + (size_t)src * 256 + part * 16;
      union { i32x4 q; u16 h[8]; } a, b;
      a.q = *(const i32x4*)(mrow);
      b.q = *(const i32x4*)(mrow + 8);
      #pragma unroll
      for (int j = 0; j < 8; ++j) {
        mx[j] = fmaxf(mx[j], bf2f(a.h[j]));
        mx[8 + j] = fmaxf(mx[8 + j], bf2f(b.h[j]));
      }
    }
    union { i32x4 q; u16 h[8]; } p0, p1;
    #pragma unroll
    for (int j = 0; j < 8; ++j) { p0.h[j] = f2bf(mx[j]); p1.h[j] = f2bf(mx[8 + j]); }
    *(i32x4*)(lds + (((u32)i * 1024 + (u32)(256 + part * 16) * 2) ^ sw)) = p0.q;
    *(i32x4*)(lds + (((u32)i * 1024 + (u32)(256 + part * 16) * 2 + 16) ^ sw)) = p1.q;
  }
  __syncthreads();
  {
    f32x4 acc[4] = {};
    for (int kt = 0; kt < 16; ++kt) {
      u32 r0 = (u32)r15;
      i32x4 a0 = *(const i32x4*)(lds + ((r0 * 1024 + (u32)kt * 64 + (u32)g * 16) ^ ((r0 & 7) << 4)));
      #pragma unroll
      for (int n4 = 0; n4 < 4; ++n4) {
        int nt = w * 4 + n4;
        i32x4 b = *(const i32x4*)(wc1f + (((size_t)(kt * 16 + nt) * 64 + lane) << 3));
        acc[n4] = MFMA(a0, b, acc[n4]);
      }
    }
    #pragma unroll
    for (int n4 = 0; n4 < 4; ++n4) {
      int col = (w * 4 + n4) * 16 + r15;
      float bv = b1v[col];
      #pragma unroll
      for (int j = 0; j < 4; ++j)
        zbuf[(g * 4 + j) * 256 + col] = acc[n4][j] + bv;
    }
  }
  __syncthreads();
  {
    int i = tid >> 4, part = tid & 15;
    float* zr = zbuf + i * 256 + part * 16;
    f32x4 v0 = *(const f32x4*)(zr + 0), v1 = *(const f32x4*)(zr + 4);
    f32x4 v2 = *(const f32x4*)(zr + 8), v3 = *(const f32x4*)(zr + 12);
    float ss = 0.0f;
    #pragma unroll
    for (int j = 0; j < 4; ++j) ss += v0[j]*v0[j] + v1[j]*v1[j] + v2[j]*v2[j] + v3[j]*v3[j];
    ss += __shfl_xor(ss, 1); ss += __shfl_xor(ss, 2);
    ss += __shfl_xor(ss, 4); ss += __shfl_xor(ss, 8);
    float rn = 1.0f / fmaxf(sqrtf(ss), 1e-12f);
    v0 *= rn; v1 *= rn; v2 *= rn; v3 *= rn;
    u32 sw = (u32)((i & 7) << 4);
    *(i32x4*)(lds + 32768 + (((u32)i * 512 + (u32)(part * 16) * 2) ^ sw)) = cvt8(v0, v1);
    *(i32x4*)(lds + 32768 + (((u32)i * 512 + (u32)(part * 16) * 2 + 16) ^ sw)) = cvt8(v2, v3);
  }
  __syncthreads();
  {
    f32x4 acc[4] = {};
    for (int kt = 0; kt < 8; ++kt) {
      u32 r0 = (u32)r15;
      i32x4 a0 = *(const i32x4*)(lds + 32768 + ((r0 * 512 + (u32)kt * 64 + (u32)g * 16) ^ ((r0 & 7) << 4)));
      #pragma unroll
      for (int n4 = 0; n4 < 4; ++n4) {
        int nt = w * 4 + n4;
        i32x4 b = *(const i32x4*)(wlatf + (((size_t)(kt * 16 + nt) * 64 + lane) << 3));
        acc[n4] = MFMA(a0, b, acc[n4]);
      }
    }
    #pragma unroll
    for (int n4 = 0; n4 < 4; ++n4) {
      int col = (w * 4 + n4) * 16 + r15;
      float bv = blat[col];
      #pragma unroll
      for (int j = 0; j < 4; ++j)
        zbuf[(g * 4 + j) * 256 + col] = acc[n4][j] + bv;
    }
  }
  __syncthreads();
  {
    int i = tid >> 4, part = tid & 15;
    float* zr = zbuf + i * 256 + part * 16;
    float* orow = zz + (size_t)(d0 + i) * 256 + part * 16;
    #pragma unroll
    for (int c = 0; c < 16; c += 4) *(f32x4*)(orow + c) = *(const f32x4*)(zr + c);
  }
  {
    int c = tid; float s1 = 0.0f, s2 = 0.0f;
    #pragma unroll
    for (int r = 0; r < 16; ++r) { float v = zbuf[r * 256 + c]; s1 += v; s2 += v * v; }
    atomicAdd(&statl[c], s1); atomicAdd(&statl[256 + c], s2);
  }
}

// ---------------- K7: out = bnl(zz) (kfin folded in) ----------------
__global__ void k7_out(const float* __restrict__ zz, const float* __restrict__ statl,
                       const float* __restrict__ gg, const float* __restrict__ bb,
                       float* __restrict__ out) {
  int idx = blockIdx.x * 256 + threadIdx.x;
  int e0 = idx * 4;
  int c = e0 & 255;
  const float inv_n = 1.0f / (float)CN2;
  f32x4 s1 = *(const f32x4*)(statl + c);
  f32x4 s2 = *(const f32x4*)(statl + 256 + c);
  f32x4 gv = *(const f32x4*)(gg + c);
  f32x4 bv = *(const f32x4*)(bb + c);
  f32x4 v = *(const f32x4*)(zz + e0);
  f32x4 o;
  #pragma unroll
  for (int j = 0; j < 4; ++j) {
    float mu = s1[j] * inv_n;
    float var = s2[j] * inv_n - mu * mu;
    float sc = gv[j] / sqrtf(var + 1e-5f);
    o[j] = v[j] * sc + (bv[j] - mu * sc);
  }
  *(f32x4*)(out + e0) = o;
}

extern "C" void kernel_launch(void* const* d_in, const int* in_sizes, int n_in,
                              void* d_out, int out_size, void* d_ws, size_t ws_size,
                              hipStream_t stream) {
  const float* x     = (const float*)d_in[0];
  const int*   es0   = (const int*)d_in[1];
  const int*   es1   = (const int*)d_in[3];
  const float* Wp0   = (const float*)d_in[5];
  const float* bp0   = (const float*)d_in[6];
  const float* Ws0   = (const float*)d_in[7];
  const float* Wn0   = (const float*)d_in[8];
  const float* b0v   = (const float*)d_in[9];
  const float* Wp1   = (const float*)d_in[10];
  const float* bp1   = (const float*)d_in[11];
  const float* Ws1   = (const float*)d_in[12];
  const float* Wn1   = (const float*)d_in[13];
  const float* b1v   = (const float*)d_in[14];
  const float* gbn0  = (const float*)d_in[15];
  const float* bebn0 = (const float*)d_in[16];
  const float* Wh    = (const float*)d_in[17];
  const float* bh    = (const float*)d_in[18];
  const float* gbnh  = (const float*)d_in[19];
  const float* bebnh = (const float*)d_in[20];
  const float* Wlat  = (const float*)d_in[21];
  const float* blat  = (const float*)d_in[22];
  const float* gbnl  = (const float*)d_in[23];
  const float* bebnl = (const float*)d_in[24];

  char* ws = (char*)d_ws;
  u16* h0    = (u16*)(ws + H0_OFF);
  u16* tban  = (u16*)(ws + T_OFF);
  u16* m1    = (u16*)(ws + H0_OFF);   // reuse: h0 dead after hidden GEMM
  u16* h2    = (u16*)(ws + H2_OFF);
  float* zz  = (float*)(ws + ZZ_OFF);
  u16* wp0f  = (u16*)(ws + WP0F_OFF);
  u16* wc0f  = (u16*)(ws + WC0F_OFF);
  u16* whf   = (u16*)(ws + WHF_OFF);
  u16* wp1f  = (u16*)(ws + WP1F_OFF);
  u16* wc1f  = (u16*)(ws + WC1F_OFF);
  u16* wlatf = (u16*)(ws + WLATF_OFF);
  float* stat = (float*)(ws + STAT_OFF);
  u16* Mt    = (u16*)(ws + M_OFF);

  kprep<<<64, 256, 0, stream>>>(Wp0, Ws0, Wn0, Wh, Wp1, Ws1, Wn1, Wlat,
                                wp0f, wc0f, whf, wp1f, wc1f, wlatf, stat);
  if (ws_size >= M_OFF + M_BYTES) {
    kM<<<CN0 / 64, 256, 0, stream>>>(x, wp0f, bp0, Mt);
    k1b<<<CN1 / 32, 256, 0, stream>>>(Mt, x, es0, wc0f, b0v, h0, stat);
  } else {
    k1_layer0<<<CN1 / 32, 256, 0, stream>>>(x, es0, wp0f, wc0f, bp0, b0v, h0, stat);
  }
  gemm64<false, true, false><<<CN1 / 64, 256, 0, stream>>>(
      h0, stat, 1.0f / CN1, gbn0, bebn0, whf, bh, tban, stat + 512, nullptr);
  gemm64<true, false, true><<<CN1 / 64, 256, 0, stream>>>(
      tban, stat + 512, 1.0f / CN1, gbnh, bebnh, wp1f, bp1, m1, nullptr, h2);
  k6_layer1<<<CN2 / 16, 256, 0, stream>>>(es1, m1, h2, wc1f, wlatf, b1v, blat, zz,
                                          stat + 1024);
  k7_out<<<out_size / 1024, 256, 0, stream>>>(zz, stat + 1024, gbnl, bebnl,
                                              (float*)d_out);
  (void)in_sizes; (void)n_in;
}

// Round 6
// 273.808 us; speedup vs baseline: 1.3988x; 1.3988x over previous
//
#include <hip/hip_runtime.h>

typedef unsigned short u16;
typedef unsigned int u32;
typedef float f32x4 __attribute__((ext_vector_type(4)));
typedef int i32x4 __attribute__((ext_vector_type(4)));
typedef __bf16 bf16x8 __attribute__((ext_vector_type(8)));
typedef short s16x8 __attribute__((ext_vector_type(8)));

#define CN0 655360
#define CN1 81920
#define CN2 8192

// ---------------- ws layout (bytes) ----------------
#define H0_OFF    0ull            // u16[81920*256] (l2normed layer0 out; later reused as m1)
#define T_OFF     41943040ull     // u16[81920*256] (hidden pre-bn t)
#define H2_OFF    83886080ull     // u16[8192*256]  (relu(bnh(t)) head rows)
#define ZZ_OFF    88080384ull     // f32[8192*256]  (pre-bnl latent)
#define WP0F_OFF  96468992ull     // u16[128*128] frag
#define WC0F_OFF  96501760ull     // u16[256*256] frag [Wself0;Wneigh0]
#define WHF_OFF   96632832ull     // u16[256*256] frag
#define WP1F_OFF  96763904ull     // u16[256*256] frag
#define WC1F_OFF  96894976ull     // u16[512*256] frag [Wself1;Wneigh1]
#define WLATF_OFF 97157120ull     // u16[256*256] frag
#define STAT_OFF  97288192ull     // f32[6*256]: bn0 sum/sumsq, bnh, bnl

__device__ inline u16 f2bf(float f) {
  u32 u = __builtin_bit_cast(u32, f);
  return (u16)((u + 0x7fffu + ((u >> 16) & 1u)) >> 16);  // RNE
}
__device__ inline float bf2f(u16 s) {
  return __builtin_bit_cast(float, (u32)s << 16);
}
// 8×f32 -> packed bf16x8 (compiler emits v_cvt_pk_bf16_f32)
__device__ inline i32x4 cvt8(f32x4 a, f32x4 b) {
  union { bf16x8 v; i32x4 q; } u;
  #pragma unroll
  for (int j = 0; j < 4; ++j) { u.v[j] = (__bf16)a[j]; u.v[4 + j] = (__bf16)b[j]; }
  return u.q;
}

// MFMA shim: gfx950 builtin takes either v8bf16 or v8i16 depending on
// toolchain; SFINAE picks whichever compiles.
template <typename V>
__device__ inline auto mfma_sel(V a, V b, f32x4 c, int)
    -> decltype(__builtin_amdgcn_mfma_f32_16x16x32_bf16(a, b, c, 0, 0, 0)) {
  return __builtin_amdgcn_mfma_f32_16x16x32_bf16(a, b, c, 0, 0, 0);
}
template <typename V>
__device__ inline f32x4 mfma_sel(V a, V b, f32x4 c, long) {
  return __builtin_amdgcn_mfma_f32_16x16x32_bf16(
      __builtin_bit_cast(s16x8, a), __builtin_bit_cast(s16x8, b), c, 0, 0, 0);
}
__device__ inline f32x4 MFMA(i32x4 a, i32x4 b, f32x4 c) {
  return mfma_sel(__builtin_bit_cast(bf16x8, a), __builtin_bit_cast(bf16x8, b), c, 0);
}

// ---------------- weight prep: bf16 + MFMA-B fragment order ----------------
// storage [kt][nt][lane][j]; value = B[kt*32 + 8*(lane>>4) + j][nt*16 + (lane&15)]
__device__ void fragify(const float* W0, const float* W1, int Khalf, int N,
                        u16* dst, int tid, int nthr) {
  int K = W1 ? 2 * Khalf : Khalf;
  int ntile = N >> 4;
  int total = (K >> 5) * ntile * 512;
  for (int i = tid; i < total; i += nthr) {
    int j = i & 7;
    int lane = (i >> 3) & 63;
    int nt = (i >> 9) % ntile;
    int kt = i / (512 * ntile);
    int k = kt * 32 + ((lane >> 4) << 3) + j;
    int n = nt * 16 + (lane & 15);
    float v = (k < Khalf) ? W0[k * N + n] : W1[(k - Khalf) * N + n];
    dst[i] = f2bf(v);
  }
}

__global__ void kprep(const float* Wp0, const float* Ws0, const float* Wn0,
                      const float* Wh, const float* Wp1, const float* Ws1,
                      const float* Wn1, const float* Wlat,
                      u16* wp0f, u16* wc0f, u16* whf, u16* wp1f, u16* wc1f,
                      u16* wlatf, float* stat) {
  int tid = blockIdx.x * blockDim.x + threadIdx.x;
  int nthr = gridDim.x * blockDim.x;
  if (blockIdx.x == 0) {
    #pragma unroll
    for (int i = 0; i < 6; ++i) stat[threadIdx.x + i * 256] = 0.0f;
  }
  fragify(Wp0, nullptr, 128, 128, wp0f, tid, nthr);
  fragify(Ws0, Wn0, 128, 256, wc0f, tid, nthr);
  fragify(Wh, nullptr, 256, 256, whf, tid, nthr);
  fragify(Wp1, nullptr, 256, 256, wp1f, tid, nthr);
  fragify(Ws1, Wn1, 256, 256, wc1f, tid, nthr);
  fragify(Wlat, nullptr, 256, 256, wlatf, tid, nthr);
}

// ---------------- K1: fused layer-0 SAGE (32 dst / block) ----------------
// R2-measured-best structure: gather-first (32 independent 16B loads/thread
// issued before any dependent use), x_dst loaded in phase B, bounds(256,3)
// so the compiler keeps ~88 VGPR of load payload in flight.
__global__ __launch_bounds__(256, 3)
void k1_layer0(const float* __restrict__ x, const int* __restrict__ esrc,
               const u16* __restrict__ wp0f, const u16* __restrict__ wc0f,
               const float* __restrict__ bp0, const float* __restrict__ b0v,
               u16* __restrict__ h0, float* __restrict__ stat0) {
  __shared__ __align__(16) char lds[16896];  // u [32][256]bf16 @0; rowsum f32[32][4] @16384
  float* rsb = (float*)(lds + 16384);
  int tid = threadIdx.x, lane = tid & 63, w = tid >> 6;
  int r15 = lane & 15, g = lane >> 4;
  int d0 = blockIdx.x * 32;

  // ---- phase A: gather A-fragments from global, m = relu(row@Wp0+bp0), segmax(8)
  {
    int e0 = d0 * 8 + w * 64;
    const float* rp[4];
    #pragma unroll
    for (int rt = 0; rt < 4; ++rt)
      rp[rt] = x + (size_t)esrc[e0 + rt * 16 + r15] * 128;
    i32x4 afr[4][4];
    #pragma unroll
    for (int rt = 0; rt < 4; ++rt)
      #pragma unroll
      for (int kt = 0; kt < 4; ++kt) {
        f32x4 p0 = *(const f32x4*)(rp[rt] + kt * 32 + g * 8);
        f32x4 p1 = *(const f32x4*)(rp[rt] + kt * 32 + g * 8 + 4);
        afr[rt][kt] = cvt8(p0, p1);
      }
    for (int nt = 0; nt < 8; ++nt) {
      f32x4 acc[4] = {};
      #pragma unroll
      for (int kt = 0; kt < 4; ++kt) {
        i32x4 b = *(const i32x4*)(wp0f + (((kt * 8 + nt) * 64 + lane) << 3));
        #pragma unroll
        for (int rt = 0; rt < 4; ++rt) acc[rt] = MFMA(afr[rt][kt], b, acc[rt]);
      }
      float bias = bp0[nt * 16 + r15];
      #pragma unroll
      for (int rt = 0; rt < 4; ++rt) {
        float mx = fmaxf(fmaxf(acc[rt][0], acc[rt][1]), fmaxf(acc[rt][2], acc[rt][3]));
        mx = fmaxf(mx + bias, 0.0f);                 // relu(max+b) == max(relu(v+b))
        mx = fmaxf(mx, __shfl_xor(mx, 16));          // combine 4+4 edge rows
        if ((g & 1) == 0) {
          u32 row = (u32)(w * 8 + rt * 2 + (g >> 1));
          u32 byte = (row * 512 + 256 + (u32)(nt * 16 + r15) * 2) ^ ((row & 7) << 4);
          *(u16*)(lds + byte) = f2bf(mx);
        }
      }
    }
  }

  // ---- phase B build: u[0:128] = x_dst (bf16, swizzled)
  {
    int i = tid >> 3, part = tid & 7;
    const float* xr = x + (size_t)(d0 + i) * 128 + part * 16;
    f32x4 t0 = *(const f32x4*)(xr + 0);
    f32x4 t1 = *(const f32x4*)(xr + 4);
    f32x4 t2 = *(const f32x4*)(xr + 8);
    f32x4 t3 = *(const f32x4*)(xr + 12);
    u32 sw = (u32)((i & 7) << 4);
    *(i32x4*)(lds + (((u32)i * 512 + (u32)part * 32) ^ sw)) = cvt8(t0, t1);
    *(i32x4*)(lds + (((u32)i * 512 + (u32)part * 32 + 16) ^ sw)) = cvt8(t2, t3);
  }
  __syncthreads();

  // ---- phase B GEMM: h0row = u @ Wcat0 + b0 (K=256)
  f32x4 acc2[4][2] = {};
  for (int kt = 0; kt < 8; ++kt) {
    u32 r0 = (u32)r15, r1 = (u32)(16 + r15);
    i32x4 a0 = *(const i32x4*)(lds + ((r0 * 512 + (u32)kt * 64 + (u32)g * 16) ^ ((r0 & 7) << 4)));
    i32x4 a1 = *(const i32x4*)(lds + ((r1 * 512 + (u32)kt * 64 + (u32)g * 16) ^ ((r1 & 7) << 4)));
    #pragma unroll
    for (int n4 = 0; n4 < 4; ++n4) {
      int nt = w * 4 + n4;
      i32x4 b = *(const i32x4*)(wc0f + (((size_t)(kt * 16 + nt) * 64 + lane) << 3));
      acc2[n4][0] = MFMA(a0, b, acc2[n4][0]);
      acc2[n4][1] = MFMA(a1, b, acc2[n4][1]);
    }
  }

  // ---- epilogue: bias, l2norm (register), bn0 stats, bf16 store
  float vn[4][2][4];
  #pragma unroll
  for (int n4 = 0; n4 < 4; ++n4) {
    float bv = b0v[(w * 4 + n4) * 16 + r15];
    #pragma unroll
    for (int rt = 0; rt < 2; ++rt)
      #pragma unroll
      for (int j = 0; j < 4; ++j) vn[n4][rt][j] = acc2[n4][rt][j] + bv;
  }
  #pragma unroll
  for (int rt = 0; rt < 2; ++rt)
    #pragma unroll
    for (int j = 0; j < 4; ++j) {
      float s = 0.0f;
      #pragma unroll
      for (int n4 = 0; n4 < 4; ++n4) s += vn[n4][rt][j] * vn[n4][rt][j];
      s += __shfl_xor(s, 1); s += __shfl_xor(s, 2);
      s += __shfl_xor(s, 4); s += __shfl_xor(s, 8);
      if (r15 == 0) rsb[(rt * 16 + g * 4 + j) * 4 + w] = s;
    }
  __syncthreads();   // rowsums ready; u-LDS now dead

  #pragma unroll
  for (int rt = 0; rt < 2; ++rt)
    #pragma unroll
    for (int j = 0; j < 4; ++j) {
      int r = rt * 16 + g * 4 + j;
      f32x4 q = *(const f32x4*)&rsb[r * 4];
      float rn = 1.0f / fmaxf(sqrtf(q[0] + q[1] + q[2] + q[3]), 1e-12f);
      #pragma unroll
      for (int n4 = 0; n4 < 4; ++n4) vn[n4][rt][j] *= rn;
    }
  // bn0 stats (per-col partial over this block's 32 rows)
  #pragma unroll
  for (int n4 = 0; n4 < 4; ++n4) {
    int col = (w * 4 + n4) * 16 + r15;
    float s1 = 0.0f, s2 = 0.0f;
    #pragma unroll
    for (int rt = 0; rt < 2; ++rt)
      #pragma unroll
      for (int j = 0; j < 4; ++j) { float v = vn[n4][rt][j]; s1 += v; s2 += v * v; }
    s1 += __shfl_xor(s1, 16); s1 += __shfl_xor(s1, 32);
    s2 += __shfl_xor(s2, 16); s2 += __shfl_xor(s2, 32);
    if (g == 0) { atomicAdd(&stat0[col], s1); atomicAdd(&stat0[256 + col], s2); }
  }
  // stage bf16 rows in u-region (plain layout) for coalesced store
  #pragma unroll
  for (int n4 = 0; n4 < 4; ++n4)
    #pragma unroll
    for (int rt = 0; rt < 2; ++rt)
      #pragma unroll
      for (int j = 0; j < 4; ++j)
        *(u16*)(lds + (u32)(rt * 16 + g * 4 + j) * 512 + (u32)((w * 4 + n4) * 16 + r15) * 2)
            = f2bf(vn[n4][rt][j]);
  __syncthreads();
  {
    int i = tid >> 3, c8 = tid & 7;
    const char* srcp = lds + i * 512 + c8 * 64;
    u16* dst = h0 + (size_t)(d0 + i) * 256 + c8 * 32;
    #pragma unroll
    for (int c = 0; c < 4; ++c)
      *(i32x4*)(dst + c * 8) = *(const i32x4*)(srcp + c * 16);
  }
}

// ---------------- gemm64: Out = [relu(bn(Ain))] @ Bf + bias ----------------
// BN scale/shift computed in-kernel from raw sums (kfin folded in).
template <bool RELU_OUT, bool STATS, bool H2OUT>
__global__ __launch_bounds__(256, 4)
void gemm64(const u16* __restrict__ Ain, const float* __restrict__ statin,
            float inv_n, const float* __restrict__ gg, const float* __restrict__ bb,
            const u16* __restrict__ Bf, const float* __restrict__ bias,
            u16* __restrict__ Out, float* __restrict__ statout,
            u16* __restrict__ H2out) {
  __shared__ __align__(16) char lds[34816];  // A-stage/tb share [0,32768); scs @32768
  u16* tb = (u16*)lds;
  float* scs = (float*)(lds + 32768);
  int tid = threadIdx.x, lane = tid & 63, w = tid >> 6;
  int r15 = lane & 15, g = lane >> 4;
  int d0 = blockIdx.x * 64;
  {
    float mu = statin[tid] * inv_n;
    float var = statin[256 + tid] * inv_n - mu * mu;
    float sc = gg[tid] / sqrtf(var + 1e-5f);
    scs[tid] = sc;
    scs[256 + tid] = bb[tid] - mu * sc;
  }
  __syncthreads();
  {
    int i = tid >> 2, part = tid & 3;
    const u16* ar = Ain + (size_t)(d0 + i) * 256 + part * 64;
    u32 sw = (u32)((i & 7) << 4), rowb = (u32)i * 512;
    for (int cc = 0; cc < 8; ++cc) {
      union { i32x4 q; u16 h[8]; } in, out;
      in.q = *(const i32x4*)(ar + cc * 8);
      #pragma unroll
      for (int j = 0; j < 8; ++j) {
        int k = part * 64 + cc * 8 + j;
        float v = fmaxf(bf2f(in.h[j]) * scs[k] + scs[256 + k], 0.0f);
        out.h[j] = f2bf(v);
      }
      *(i32x4*)(lds + ((rowb + (u32)(part * 64 + cc * 8) * 2) ^ sw)) = out.q;
    }
  }
  __syncthreads();

  f32x4 acc[4][4] = {};
  for (int kt = 0; kt < 8; ++kt) {
    i32x4 a[4];
    #pragma unroll
    for (int rt = 0; rt < 4; ++rt) {
      u32 r = (u32)(rt * 16 + r15);
      a[rt] = *(const i32x4*)(lds + ((r * 512 + (u32)kt * 64 + (u32)g * 16) ^ ((r & 7) << 4)));
    }
    #pragma unroll
    for (int n4 = 0; n4 < 4; ++n4) {
      int nt = w * 4 + n4;
      i32x4 b = *(const i32x4*)(Bf + (((size_t)(kt * 16 + nt) * 64 + lane) << 3));
      #pragma unroll
      for (int rt = 0; rt < 4; ++rt) acc[n4][rt] = MFMA(a[rt], b, acc[n4][rt]);
    }
  }
  __syncthreads();

  if constexpr (H2OUT) {
    if (d0 < CN2) {
      int i = tid >> 2, part = tid & 3;
      u16* orow = H2out + (size_t)(d0 + i) * 256 + part * 64;
      u32 sw = (u32)((i & 7) << 4);
      #pragma unroll
      for (int cc = 0; cc < 8; ++cc)
        *(i32x4*)(orow + cc * 8) =
            *(const i32x4*)(lds + (((u32)i * 512 + (u32)(part * 64 + cc * 8) * 2) ^ sw));
    }
    __syncthreads();
  }

  #pragma unroll
  for (int n4 = 0; n4 < 4; ++n4) {
    int col = (w * 4 + n4) * 16 + r15;
    float bv = bias[col];
    #pragma unroll
    for (int rt = 0; rt < 4; ++rt)
      #pragma unroll
      for (int j = 0; j < 4; ++j) {
        float v = acc[n4][rt][j] + bv;
        if (RELU_OUT) v = fmaxf(v, 0.0f);
        tb[(rt * 16 + g * 4 + j) * 256 + col] = f2bf(v);
      }
  }
  __syncthreads();

  {
    int i = tid >> 2, part = tid & 3;
    u16* orow = Out + (size_t)(d0 + i) * 256 + part * 64;
    const u16* trow = tb + i * 256 + part * 64;
    #pragma unroll
    for (int cc = 0; cc < 8; ++cc)
      *(i32x4*)(orow + cc * 8) = *(const i32x4*)(trow + cc * 8);
  }
  if (STATS) {
    int c = tid; float s1 = 0.0f, s2 = 0.0f;
    for (int r = 0; r < 64; ++r) { float v = bf2f(tb[r * 256 + c]); s1 += v; s2 += v * v; }
    atomicAdd(&statout[c], s1); atomicAdd(&statout[256 + c], s2);
  }
}

// ---------------- K6: fused layer-1 (16 dst / block, 4 blocks/CU) ----------------
__global__ __launch_bounds__(256, 4)
void k6_layer1(const int* __restrict__ esrc1, const u16* __restrict__ m1,
               const u16* __restrict__ h2, const u16* __restrict__ wc1f,
               const u16* __restrict__ wlatf, const float* __restrict__ b1v,
               const float* __restrict__ blat, float* __restrict__ zz,
               float* __restrict__ statl) {
  __shared__ __align__(16) char lds[40960];
  float* zbuf = (float*)(lds + 16384);
  int tid = threadIdx.x, lane = tid & 63, w = tid >> 6;
  int r15 = lane & 15, g = lane >> 4;
  int d0 = blockIdx.x * 16;
  {
    int i = tid >> 4, part = tid & 15;
    u32 sw = (u32)((i & 7) << 4);
    const u16* hrow = h2 + (size_t)(d0 + i) * 256 + part * 16;
    i32x4 q0 = *(const i32x4*)(hrow);
    i32x4 q1 = *(const i32x4*)(hrow + 8);
    *(i32x4*)(lds + (((u32)i * 1024 + (u32)(part * 16) * 2) ^ sw)) = q0;
    *(i32x4*)(lds + (((u32)i * 1024 + (u32)(part * 16) * 2 + 16) ^ sw)) = q1;
    float mx[16];
    #pragma unroll
    for (int c = 0; c < 16; ++c) mx[c] = -1e30f;
    const int* ep = esrc1 + (d0 + i) * 10;
    #pragma unroll 2
    for (int e = 0; e < 10; ++e) {
      int src = ep[e];
      const u16* mrow = m1 + (size_t)src * 256 + part * 16;
      union { i32x4 q; u16 h[8]; } a, b;
      a.q = *(const i32x4*)(mrow);
      b.q = *(const i32x4*)(mrow + 8);
      #pragma unroll
      for (int j = 0; j < 8; ++j) {
        mx[j] = fmaxf(mx[j], bf2f(a.h[j]));
        mx[8 + j] = fmaxf(mx[8 + j], bf2f(b.h[j]));
      }
    }
    union { i32x4 q; u16 h[8]; } p0, p1;
    #pragma unroll
    for (int j = 0; j < 8; ++j) { p0.h[j] = f2bf(mx[j]); p1.h[j] = f2bf(mx[8 + j]); }
    *(i32x4*)(lds + (((u32)i * 1024 + (u32)(256 + part * 16) * 2) ^ sw)) = p0.q;
    *(i32x4*)(lds + (((u32)i * 1024 + (u32)(256 + part * 16) * 2 + 16) ^ sw)) = p1.q;
  }
  __syncthreads();
  {
    f32x4 acc[4] = {};
    for (int kt = 0; kt < 16; ++kt) {
      u32 r0 = (u32)r15;
      i32x4 a0 = *(const i32x4*)(lds + ((r0 * 1024 + (u32)kt * 64 + (u32)g * 16) ^ ((r0 & 7) << 4)));
      #pragma unroll
      for (int n4 = 0; n4 < 4; ++n4) {
        int nt = w * 4 + n4;
        i32x4 b = *(const i32x4*)(wc1f + (((size_t)(kt * 16 + nt) * 64 + lane) << 3));
        acc[n4] = MFMA(a0, b, acc[n4]);
      }
    }
    #pragma unroll
    for (int n4 = 0; n4 < 4; ++n4) {
      int col = (w * 4 + n4) * 16 + r15;
      float bv = b1v[col];
      #pragma unroll
      for (int j = 0; j < 4; ++j)
        zbuf[(g * 4 + j) * 256 + col] = acc[n4][j] + bv;
    }
  }
  __syncthreads();
  {
    int i = tid >> 4, part = tid & 15;
    float* zr = zbuf + i * 256 + part * 16;
    f32x4 v0 = *(const f32x4*)(zr + 0), v1 = *(const f32x4*)(zr + 4);
    f32x4 v2 = *(const f32x4*)(zr + 8), v3 = *(const f32x4*)(zr + 12);
    float ss = 0.0f;
    #pragma unroll
    for (int j = 0; j < 4; ++j) ss += v0[j]*v0[j] + v1[j]*v1[j] + v2[j]*v2[j] + v3[j]*v3[j];
    ss += __shfl_xor(ss, 1); ss += __shfl_xor(ss, 2);
    ss += __shfl_xor(ss, 4); ss += __shfl_xor(ss, 8);
    float rn = 1.0f / fmaxf(sqrtf(ss), 1e-12f);
    v0 *= rn; v1 *= rn; v2 *= rn; v3 *= rn;
    u32 sw = (u32)((i & 7) << 4);
    *(i32x4*)(lds + 32768 + (((u32)i * 512 + (u32)(part * 16) * 2) ^ sw)) = cvt8(v0, v1);
    *(i32x4*)(lds + 32768 + (((u32)i * 512 + (u32)(part * 16) * 2 + 16) ^ sw)) = cvt8(v2, v3);
  }
  __syncthreads();
  {
    f32x4 acc[4] = {};
    for (int kt = 0; kt < 8; ++kt) {
      u32 r0 = (u32)r15;
      i32x4 a0 = *(const i32x4*)(lds + 32768 + ((r0 * 512 + (u32)kt * 64 + (u32)g * 16) ^ ((r0 & 7) << 4)));
      #pragma unroll
      for (int n4 = 0; n4 < 4; ++n4) {
        int nt = w * 4 + n4;
        i32x4 b = *(const i32x4*)(wlatf + (((size_t)(kt * 16 + nt) * 64 + lane) << 3));
        acc[n4] = MFMA(a0, b, acc[n4]);
      }
    }
    #pragma unroll
    for (int n4 = 0; n4 < 4; ++n4) {
      int col = (w * 4 + n4) * 16 + r15;
      float bv = blat[col];
      #pragma unroll
      for (int j = 0; j < 4; ++j)
        zbuf[(g * 4 + j) * 256 + col] = acc[n4][j] + bv;
    }
  }
  __syncthreads();
  {
    int i = tid >> 4, part = tid & 15;
    float* zr = zbuf + i * 256 + part * 16;
    float* orow = zz + (size_t)(d0 + i) * 256 + part * 16;
    #pragma unroll
    for (int c = 0; c < 16; c += 4) *(f32x4*)(orow + c) = *(const f32x4*)(zr + c);
  }
  {
    int c = tid; float s1 = 0.0f, s2 = 0.0f;
    #pragma unroll
    for (int r = 0; r < 16; ++r) { float v = zbuf[r * 256 + c]; s1 += v; s2 += v * v; }
    atomicAdd(&statl[c], s1); atomicAdd(&statl[256 + c], s2);
  }
}

// ---------------- K7: out = bnl(zz) (kfin folded in) ----------------
__global__ void k7_out(const float* __restrict__ zz, const float* __restrict__ statl,
                       const float* __restrict__ gg, const float* __restrict__ bb,
                       float* __restrict__ out) {
  int idx = blockIdx.x * 256 + threadIdx.x;
  int e0 = idx * 4;
  int c = e0 & 255;
  const float inv_n = 1.0f / (float)CN2;
  f32x4 s1 = *(const f32x4*)(statl + c);
  f32x4 s2 = *(const f32x4*)(statl + 256 + c);
  f32x4 gv = *(const f32x4*)(gg + c);
  f32x4 bv = *(const f32x4*)(bb + c);
  f32x4 v = *(const f32x4*)(zz + e0);
  f32x4 o;
  #pragma unroll
  for (int j = 0; j < 4; ++j) {
    float mu = s1[j] * inv_n;
    float var = s2[j] * inv_n - mu * mu;
    float sc = gv[j] / sqrtf(var + 1e-5f);
    o[j] = v[j] * sc + (bv[j] - mu * sc);
  }
  *(f32x4*)(out + e0) = o;
}

extern "C" void kernel_launch(void* const* d_in, const int* in_sizes, int n_in,
                              void* d_out, int out_size, void* d_ws, size_t ws_size,
                              hipStream_t stream) {
  const float* x     = (const float*)d_in[0];
  const int*   es0   = (const int*)d_in[1];
  const int*   es1   = (const int*)d_in[3];
  const float* Wp0   = (const float*)d_in[5];
  const float* bp0   = (const float*)d_in[6];
  const float* Ws0   = (const float*)d_in[7];
  const float* Wn0   = (const float*)d_in[8];
  const float* b0v   = (const float*)d_in[9];
  const float* Wp1   = (const float*)d_in[10];
  const float* bp1   = (const float*)d_in[11];
  const float* Ws1   = (const float*)d_in[12];
  const float* Wn1   = (const float*)d_in[13];
  const float* b1v   = (const float*)d_in[14];
  const float* gbn0  = (const float*)d_in[15];
  const float* bebn0 = (const float*)d_in[16];
  const float* Wh    = (const float*)d_in[17];
  const float* bh    = (const float*)d_in[18];
  const float* gbnh  = (const float*)d_in[19];
  const float* bebnh = (const float*)d_in[20];
  const float* Wlat  = (const float*)d_in[21];
  const float* blat  = (const float*)d_in[22];
  const float* gbnl  = (const float*)d_in[23];
  const float* bebnl = (const float*)d_in[24];

  char* ws = (char*)d_ws;
  u16* h0    = (u16*)(ws + H0_OFF);
  u16* tban  = (u16*)(ws + T_OFF);
  u16* m1    = (u16*)(ws + H0_OFF);   // reuse: h0 dead after hidden GEMM
  u16* h2    = (u16*)(ws + H2_OFF);
  float* zz  = (float*)(ws + ZZ_OFF);
  u16* wp0f  = (u16*)(ws + WP0F_OFF);
  u16* wc0f  = (u16*)(ws + WC0F_OFF);
  u16* whf   = (u16*)(ws + WHF_OFF);
  u16* wp1f  = (u16*)(ws + WP1F_OFF);
  u16* wc1f  = (u16*)(ws + WC1F_OFF);
  u16* wlatf = (u16*)(ws + WLATF_OFF);
  float* stat = (float*)(ws + STAT_OFF);

  kprep<<<64, 256, 0, stream>>>(Wp0, Ws0, Wn0, Wh, Wp1, Ws1, Wn1, Wlat,
                                wp0f, wc0f, whf, wp1f, wc1f, wlatf, stat);
  k1_layer0<<<CN1 / 32, 256, 0, stream>>>(x, es0, wp0f, wc0f, bp0, b0v, h0, stat);
  gemm64<false, true, false><<<CN1 / 64, 256, 0, stream>>>(
      h0, stat, 1.0f / CN1, gbn0, bebn0, whf, bh, tban, stat + 512, nullptr);
  gemm64<true, false, true><<<CN1 / 64, 256, 0, stream>>>(
      tban, stat + 512, 1.0f / CN1, gbnh, bebnh, wp1f, bp1, m1, nullptr, h2);
  k6_layer1<<<CN2 / 16, 256, 0, stream>>>(es1, m1, h2, wc1f, wlatf, b1v, blat, zz,
                                          stat + 1024);
  k7_out<<<out_size / 1024, 256, 0, stream>>>(zz, stat + 1024, gbnl, bebnl,
                                              (float*)d_out);
  (void)in_sizes; (void)n_in; (void)ws_size;
}

// Round 7
// 269.829 us; speedup vs baseline: 1.4195x; 1.0147x over previous
//
#include <hip/hip_runtime.h>

typedef unsigned short u16;
typedef unsigned int u32;
typedef float f32x4 __attribute__((ext_vector_type(4)));
typedef int i32x4 __attribute__((ext_vector_type(4)));
typedef __bf16 bf16x8 __attribute__((ext_vector_type(8)));
typedef short s16x8 __attribute__((ext_vector_type(8)));

#define CN0 655360
#define CN1 81920
#define CN2 8192

// ---------------- ws layout (bytes) ----------------
#define H0_OFF    0ull            // u16[81920*256] (l2normed layer0 out; later reused as m1)
#define T_OFF     41943040ull     // u16[81920*256] (hidden pre-bn t)
#define H2_OFF    83886080ull     // u16[8192*256]  (relu(bnh(t)) head rows)
#define ZZ_OFF    88080384ull     // f32[8192*256]  (pre-bnl latent)
#define WP0F_OFF  96468992ull     // u16[128*128] frag
#define WC0F_OFF  96501760ull     // u16[256*256] frag [Wself0;Wneigh0]
#define WHF_OFF   96632832ull     // u16[256*256] frag
#define WP1F_OFF  96763904ull     // u16[256*256] frag
#define WC1F_OFF  96894976ull     // u16[512*256] frag [Wself1;Wneigh1]
#define WLATF_OFF 97157120ull     // u16[256*256] frag
#define STAT_OFF  97288192ull     // f32[6*256]: bn0 sum/sumsq, bnh, bnl

__device__ inline u16 f2bf(float f) {
  u32 u = __builtin_bit_cast(u32, f);
  return (u16)((u + 0x7fffu + ((u >> 16) & 1u)) >> 16);  // RNE
}
__device__ inline float bf2f(u16 s) {
  return __builtin_bit_cast(float, (u32)s << 16);
}
// 8×f32 -> packed bf16x8 (compiler emits v_cvt_pk_bf16_f32)
__device__ inline i32x4 cvt8(f32x4 a, f32x4 b) {
  union { bf16x8 v; i32x4 q; } u;
  #pragma unroll
  for (int j = 0; j < 4; ++j) { u.v[j] = (__bf16)a[j]; u.v[4 + j] = (__bf16)b[j]; }
  return u.q;
}

// MFMA shim: gfx950 builtin takes either v8bf16 or v8i16 depending on
// toolchain; SFINAE picks whichever compiles.
template <typename V>
__device__ inline auto mfma_sel(V a, V b, f32x4 c, int)
    -> decltype(__builtin_amdgcn_mfma_f32_16x16x32_bf16(a, b, c, 0, 0, 0)) {
  return __builtin_amdgcn_mfma_f32_16x16x32_bf16(a, b, c, 0, 0, 0);
}
template <typename V>
__device__ inline f32x4 mfma_sel(V a, V b, f32x4 c, long) {
  return __builtin_amdgcn_mfma_f32_16x16x32_bf16(
      __builtin_bit_cast(s16x8, a), __builtin_bit_cast(s16x8, b), c, 0, 0, 0);
}
__device__ inline f32x4 MFMA(i32x4 a, i32x4 b, f32x4 c) {
  return mfma_sel(__builtin_bit_cast(bf16x8, a), __builtin_bit_cast(bf16x8, b), c, 0);
}

// ---------------- weight prep: bf16 + MFMA-B fragment order ----------------
// storage [kt][nt][lane][j]; value = B[kt*32 + 8*(lane>>4) + j][nt*16 + (lane&15)]
__device__ void fragify(const float* W0, const float* W1, int Khalf, int N,
                        u16* dst, int tid, int nthr) {
  int K = W1 ? 2 * Khalf : Khalf;
  int ntile = N >> 4;
  int total = (K >> 5) * ntile * 512;
  for (int i = tid; i < total; i += nthr) {
    int j = i & 7;
    int lane = (i >> 3) & 63;
    int nt = (i >> 9) % ntile;
    int kt = i / (512 * ntile);
    int k = kt * 32 + ((lane >> 4) << 3) + j;
    int n = nt * 16 + (lane & 15);
    float v = (k < Khalf) ? W0[k * N + n] : W1[(k - Khalf) * N + n];
    dst[i] = f2bf(v);
  }
}

__global__ void kprep(const float* Wp0, const float* Ws0, const float* Wn0,
                      const float* Wh, const float* Wp1, const float* Ws1,
                      const float* Wn1, const float* Wlat,
                      u16* wp0f, u16* wc0f, u16* whf, u16* wp1f, u16* wc1f,
                      u16* wlatf, float* stat) {
  int tid = blockIdx.x * blockDim.x + threadIdx.x;
  int nthr = gridDim.x * blockDim.x;
  if (blockIdx.x == 0) {
    #pragma unroll
    for (int i = 0; i < 6; ++i) stat[threadIdx.x + i * 256] = 0.0f;
  }
  fragify(Wp0, nullptr, 128, 128, wp0f, tid, nthr);
  fragify(Ws0, Wn0, 128, 256, wc0f, tid, nthr);
  fragify(Wh, nullptr, 256, 256, whf, tid, nthr);
  fragify(Wp1, nullptr, 256, 256, wp1f, tid, nthr);
  fragify(Ws1, Wn1, 256, 256, wc1f, tid, nthr);
  fragify(Wlat, nullptr, 256, 256, wlatf, tid, nthr);
}

// ---------------- K1: fused layer-0 SAGE (32 dst / block) ----------------
// MLP experiment: bounds(256,2) -> ~256 VGPR budget; gather keeps all 32
// f32x4 loads in flight (128-VGPR payload) before ANY convert, so the
// compiler need not insert early vmcnt waits to recycle registers.
__global__ __launch_bounds__(256, 2)
void k1_layer0(const float* __restrict__ x, const int* __restrict__ esrc,
               const u16* __restrict__ wp0f, const u16* __restrict__ wc0f,
               const float* __restrict__ bp0, const float* __restrict__ b0v,
               u16* __restrict__ h0, float* __restrict__ stat0) {
  __shared__ __align__(16) char lds[16896];  // u [32][256]bf16 @0; rowsum f32[32][4] @16384
  float* rsb = (float*)(lds + 16384);
  int tid = threadIdx.x, lane = tid & 63, w = tid >> 6;
  int r15 = lane & 15, g = lane >> 4;
  int d0 = blockIdx.x * 32;

  // ---- phase A: gather A-fragments from global, m = relu(row@Wp0+bp0), segmax(8)
  {
    int e0 = d0 * 8 + w * 64;
    const float* rp[4];
    #pragma unroll
    for (int rt = 0; rt < 4; ++rt)
      rp[rt] = x + (size_t)esrc[e0 + rt * 16 + r15] * 128;
    // stage 1: issue ALL 32 independent 16B loads (no dependent ops between)
    f32x4 p[4][4][2];
    #pragma unroll
    for (int rt = 0; rt < 4; ++rt)
      #pragma unroll
      for (int kt = 0; kt < 4; ++kt) {
        p[rt][kt][0] = *(const f32x4*)(rp[rt] + kt * 32 + g * 8);
        p[rt][kt][1] = *(const f32x4*)(rp[rt] + kt * 32 + g * 8 + 4);
      }
    // stage 2: convert
    i32x4 afr[4][4];
    #pragma unroll
    for (int rt = 0; rt < 4; ++rt)
      #pragma unroll
      for (int kt = 0; kt < 4; ++kt)
        afr[rt][kt] = cvt8(p[rt][kt][0], p[rt][kt][1]);
    for (int nt = 0; nt < 8; ++nt) {
      f32x4 acc[4] = {};
      #pragma unroll
      for (int kt = 0; kt < 4; ++kt) {
        i32x4 b = *(const i32x4*)(wp0f + (((kt * 8 + nt) * 64 + lane) << 3));
        #pragma unroll
        for (int rt = 0; rt < 4; ++rt) acc[rt] = MFMA(afr[rt][kt], b, acc[rt]);
      }
      float bias = bp0[nt * 16 + r15];
      #pragma unroll
      for (int rt = 0; rt < 4; ++rt) {
        float mx = fmaxf(fmaxf(acc[rt][0], acc[rt][1]), fmaxf(acc[rt][2], acc[rt][3]));
        mx = fmaxf(mx + bias, 0.0f);                 // relu(max+b) == max(relu(v+b))
        mx = fmaxf(mx, __shfl_xor(mx, 16));          // combine 4+4 edge rows
        if ((g & 1) == 0) {
          u32 row = (u32)(w * 8 + rt * 2 + (g >> 1));
          u32 byte = (row * 512 + 256 + (u32)(nt * 16 + r15) * 2) ^ ((row & 7) << 4);
          *(u16*)(lds + byte) = f2bf(mx);
        }
      }
    }
  }

  // ---- phase B build: u[0:128] = x_dst (bf16, swizzled)
  {
    int i = tid >> 3, part = tid & 7;
    const float* xr = x + (size_t)(d0 + i) * 128 + part * 16;
    f32x4 t0 = *(const f32x4*)(xr + 0);
    f32x4 t1 = *(const f32x4*)(xr + 4);
    f32x4 t2 = *(const f32x4*)(xr + 8);
    f32x4 t3 = *(const f32x4*)(xr + 12);
    u32 sw = (u32)((i & 7) << 4);
    *(i32x4*)(lds + (((u32)i * 512 + (u32)part * 32) ^ sw)) = cvt8(t0, t1);
    *(i32x4*)(lds + (((u32)i * 512 + (u32)part * 32 + 16) ^ sw)) = cvt8(t2, t3);
  }
  __syncthreads();

  // ---- phase B GEMM: h0row = u @ Wcat0 + b0 (K=256)
  f32x4 acc2[4][2] = {};
  for (int kt = 0; kt < 8; ++kt) {
    u32 r0 = (u32)r15, r1 = (u32)(16 + r15);
    i32x4 a0 = *(const i32x4*)(lds + ((r0 * 512 + (u32)kt * 64 + (u32)g * 16) ^ ((r0 & 7) << 4)));
    i32x4 a1 = *(const i32x4*)(lds + ((r1 * 512 + (u32)kt * 64 + (u32)g * 16) ^ ((r1 & 7) << 4)));
    #pragma unroll
    for (int n4 = 0; n4 < 4; ++n4) {
      int nt = w * 4 + n4;
      i32x4 b = *(const i32x4*)(wc0f + (((size_t)(kt * 16 + nt) * 64 + lane) << 3));
      acc2[n4][0] = MFMA(a0, b, acc2[n4][0]);
      acc2[n4][1] = MFMA(a1, b, acc2[n4][1]);
    }
  }

  // ---- epilogue: bias, l2norm (register), bn0 stats, bf16 store
  float vn[4][2][4];
  #pragma unroll
  for (int n4 = 0; n4 < 4; ++n4) {
    float bv = b0v[(w * 4 + n4) * 16 + r15];
    #pragma unroll
    for (int rt = 0; rt < 2; ++rt)
      #pragma unroll
      for (int j = 0; j < 4; ++j) vn[n4][rt][j] = acc2[n4][rt][j] + bv;
  }
  #pragma unroll
  for (int rt = 0; rt < 2; ++rt)
    #pragma unroll
    for (int j = 0; j < 4; ++j) {
      float s = 0.0f;
      #pragma unroll
      for (int n4 = 0; n4 < 4; ++n4) s += vn[n4][rt][j] * vn[n4][rt][j];
      s += __shfl_xor(s, 1); s += __shfl_xor(s, 2);
      s += __shfl_xor(s, 4); s += __shfl_xor(s, 8);
      if (r15 == 0) rsb[(rt * 16 + g * 4 + j) * 4 + w] = s;
    }
  __syncthreads();   // rowsums ready; u-LDS now dead

  #pragma unroll
  for (int rt = 0; rt < 2; ++rt)
    #pragma unroll
    for (int j = 0; j < 4; ++j) {
      int r = rt * 16 + g * 4 + j;
      f32x4 q = *(const f32x4*)&rsb[r * 4];
      float rn = 1.0f / fmaxf(sqrtf(q[0] + q[1] + q[2] + q[3]), 1e-12f);
      #pragma unroll
      for (int n4 = 0; n4 < 4; ++n4) vn[n4][rt][j] *= rn;
    }
  // bn0 stats (per-col partial over this block's 32 rows)
  #pragma unroll
  for (int n4 = 0; n4 < 4; ++n4) {
    int col = (w * 4 + n4) * 16 + r15;
    float s1 = 0.0f, s2 = 0.0f;
    #pragma unroll
    for (int rt = 0; rt < 2; ++rt)
      #pragma unroll
      for (int j = 0; j < 4; ++j) { float v = vn[n4][rt][j]; s1 += v; s2 += v * v; }
    s1 += __shfl_xor(s1, 16); s1 += __shfl_xor(s1, 32);
    s2 += __shfl_xor(s2, 16); s2 += __shfl_xor(s2, 32);
    if (g == 0) { atomicAdd(&stat0[col], s1); atomicAdd(&stat0[256 + col], s2); }
  }
  // stage bf16 rows in u-region (plain layout) for coalesced store
  #pragma unroll
  for (int n4 = 0; n4 < 4; ++n4)
    #pragma unroll
    for (int rt = 0; rt < 2; ++rt)
      #pragma unroll
      for (int j = 0; j < 4; ++j)
        *(u16*)(lds + (u32)(rt * 16 + g * 4 + j) * 512 + (u32)((w * 4 + n4) * 16 + r15) * 2)
            = f2bf(vn[n4][rt][j]);
  __syncthreads();
  {
    int i = tid >> 3, c8 = tid & 7;
    const char* srcp = lds + i * 512 + c8 * 64;
    u16* dst = h0 + (size_t)(d0 + i) * 256 + c8 * 32;
    #pragma unroll
    for (int c = 0; c < 4; ++c)
      *(i32x4*)(dst + c * 8) = *(const i32x4*)(srcp + c * 16);
  }
}

// ---------------- gemm64: Out = [relu(bn(Ain))] @ Bf + bias ----------------
// BN scale/shift computed in-kernel from raw sums (kfin folded in).
template <bool RELU_OUT, bool STATS, bool H2OUT>
__global__ __launch_bounds__(256, 4)
void gemm64(const u16* __restrict__ Ain, const float* __restrict__ statin,
            float inv_n, const float* __restrict__ gg, const float* __restrict__ bb,
            const u16* __restrict__ Bf, const float* __restrict__ bias,
            u16* __restrict__ Out, float* __restrict__ statout,
            u16* __restrict__ H2out) {
  __shared__ __align__(16) char lds[34816];  // A-stage/tb share [0,32768); scs @32768
  u16* tb = (u16*)lds;
  float* scs = (float*)(lds + 32768);
  int tid = threadIdx.x, lane = tid & 63, w = tid >> 6;
  int r15 = lane & 15, g = lane >> 4;
  int d0 = blockIdx.x * 64;
  {
    float mu = statin[tid] * inv_n;
    float var = statin[256 + tid] * inv_n - mu * mu;
    float sc = gg[tid] / sqrtf(var + 1e-5f);
    scs[tid] = sc;
    scs[256 + tid] = bb[tid] - mu * sc;
  }
  __syncthreads();
  {
    int i = tid >> 2, part = tid & 3;
    const u16* ar = Ain + (size_t)(d0 + i) * 256 + part * 64;
    u32 sw = (u32)((i & 7) << 4), rowb = (u32)i * 512;
    for (int cc = 0; cc < 8; ++cc) {
      union { i32x4 q; u16 h[8]; } in, out;
      in.q = *(const i32x4*)(ar + cc * 8);
      #pragma unroll
      for (int j = 0; j < 8; ++j) {
        int k = part * 64 + cc * 8 + j;
        float v = fmaxf(bf2f(in.h[j]) * scs[k] + scs[256 + k], 0.0f);
        out.h[j] = f2bf(v);
      }
      *(i32x4*)(lds + ((rowb + (u32)(part * 64 + cc * 8) * 2) ^ sw)) = out.q;
    }
  }
  __syncthreads();

  f32x4 acc[4][4] = {};
  for (int kt = 0; kt < 8; ++kt) {
    i32x4 a[4];
    #pragma unroll
    for (int rt = 0; rt < 4; ++rt) {
      u32 r = (u32)(rt * 16 + r15);
      a[rt] = *(const i32x4*)(lds + ((r * 512 + (u32)kt * 64 + (u32)g * 16) ^ ((r & 7) << 4)));
    }
    #pragma unroll
    for (int n4 = 0; n4 < 4; ++n4) {
      int nt = w * 4 + n4;
      i32x4 b = *(const i32x4*)(Bf + (((size_t)(kt * 16 + nt) * 64 + lane) << 3));
      #pragma unroll
      for (int rt = 0; rt < 4; ++rt) acc[n4][rt] = MFMA(a[rt], b, acc[n4][rt]);
    }
  }
  __syncthreads();

  if constexpr (H2OUT) {
    if (d0 < CN2) {
      int i = tid >> 2, part = tid & 3;
      u16* orow = H2out + (size_t)(d0 + i) * 256 + part * 64;
      u32 sw = (u32)((i & 7) << 4);
      #pragma unroll
      for (int cc = 0; cc < 8; ++cc)
        *(i32x4*)(orow + cc * 8) =
            *(const i32x4*)(lds + (((u32)i * 512 + (u32)(part * 64 + cc * 8) * 2) ^ sw));
    }
    __syncthreads();
  }

  #pragma unroll
  for (int n4 = 0; n4 < 4; ++n4) {
    int col = (w * 4 + n4) * 16 + r15;
    float bv = bias[col];
    #pragma unroll
    for (int rt = 0; rt < 4; ++rt)
      #pragma unroll
      for (int j = 0; j < 4; ++j) {
        float v = acc[n4][rt][j] + bv;
        if (RELU_OUT) v = fmaxf(v, 0.0f);
        tb[(rt * 16 + g * 4 + j) * 256 + col] = f2bf(v);
      }
  }
  __syncthreads();

  {
    int i = tid >> 2, part = tid & 3;
    u16* orow = Out + (size_t)(d0 + i) * 256 + part * 64;
    const u16* trow = tb + i * 256 + part * 64;
    #pragma unroll
    for (int cc = 0; cc < 8; ++cc)
      *(i32x4*)(orow + cc * 8) = *(const i32x4*)(trow + cc * 8);
  }
  if (STATS) {
    int c = tid; float s1 = 0.0f, s2 = 0.0f;
    for (int r = 0; r < 64; ++r) { float v = bf2f(tb[r * 256 + c]); s1 += v; s2 += v * v; }
    atomicAdd(&statout[c], s1); atomicAdd(&statout[256 + c], s2);
  }
}

// ---------------- K6: fused layer-1 (16 dst / block, 4 blocks/CU) ----------------
__global__ __launch_bounds__(256, 4)
void k6_layer1(const int* __restrict__ esrc1, const u16* __restrict__ m1,
               const u16* __restrict__ h2, const u16* __restrict__ wc1f,
               const u16* __restrict__ wlatf, const float* __restrict__ b1v,
               const float* __restrict__ blat, float* __restrict__ zz,
               float* __restrict__ statl) {
  __shared__ __align__(16) char lds[40960];
  float* zbuf = (float*)(lds + 16384);
  int tid = threadIdx.x, lane = tid & 63, w = tid >> 6;
  int r15 = lane & 15, g = lane >> 4;
  int d0 = blockIdx.x * 16;
  {
    int i = tid >> 4, part = tid & 15;
    u32 sw = (u32)((i & 7) << 4);
    const u16* hrow = h2 + (size_t)(d0 + i) * 256 + part * 16;
    i32x4 q0 = *(const i32x4*)(hrow);
    i32x4 q1 = *(const i32x4*)(hrow + 8);
    *(i32x4*)(lds + (((u32)i * 1024 + (u32)(part * 16) * 2) ^ sw)) = q0;
    *(i32x4*)(lds + (((u32)i * 1024 + (u32)(part * 16) * 2 + 16) ^ sw)) = q1;
    float mx[16];
    #pragma unroll
    for (int c = 0; c < 16; ++c) mx[c] = -1e30f;
    const int* ep = esrc1 + (d0 + i) * 10;
    #pragma unroll 2
    for (int e = 0; e < 10; ++e) {
      int src = ep[e];
      const u16* mrow = m1 + (size_t)src * 256 + part * 16;
      union { i32x4 q; u16 h[8]; } a, b;
      a.q = *(const i32x4*)(mrow);
      b.q = *(const i32x4*)(mrow + 8);
      #pragma unroll
      for (int j = 0; j < 8; ++j) {
        mx[j] = fmaxf(mx[j], bf2f(a.h[j]));
        mx[8 + j] = fmaxf(mx[8 + j], bf2f(b.h[j]));
      }
    }
    union { i32x4 q; u16 h[8]; } p0, p1;
    #pragma unroll
    for (int j = 0; j < 8; ++j) { p0.h[j] = f2bf(mx[j]); p1.h[j] = f2bf(mx[8 + j]); }
    *(i32x4*)(lds + (((u32)i * 1024 + (u32)(256 + part * 16) * 2) ^ sw)) = p0.q;
    *(i32x4*)(lds + (((u32)i * 1024 + (u32)(256 + part * 16) * 2 + 16) ^ sw)) = p1.q;
  }
  __syncthreads();
  {
    f32x4 acc[4] = {};
    for (int kt = 0; kt < 16; ++kt) {
      u32 r0 = (u32)r15;
      i32x4 a0 = *(const i32x4*)(lds + ((r0 * 1024 + (u32)kt * 64 + (u32)g * 16) ^ ((r0 & 7) << 4)));
      #pragma unroll
      for (int n4 = 0; n4 < 4; ++n4) {
        int nt = w * 4 + n4;
        i32x4 b = *(const i32x4*)(wc1f + (((size_t)(kt * 16 + nt) * 64 + lane) << 3));
        acc[n4] = MFMA(a0, b, acc[n4]);
      }
    }
    #pragma unroll
    for (int n4 = 0; n4 < 4; ++n4) {
      int col = (w * 4 + n4) * 16 + r15;
      float bv = b1v[col];
      #pragma unroll
      for (int j = 0; j < 4; ++j)
        zbuf[(g * 4 + j) * 256 + col] = acc[n4][j] + bv;
    }
  }
  __syncthreads();
  {
    int i = tid >> 4, part = tid & 15;
    float* zr = zbuf + i * 256 + part * 16;
    f32x4 v0 = *(const f32x4*)(zr + 0), v1 = *(const f32x4*)(zr + 4);
    f32x4 v2 = *(const f32x4*)(zr + 8), v3 = *(const f32x4*)(zr + 12);
    float ss = 0.0f;
    #pragma unroll
    for (int j = 0; j < 4; ++j) ss += v0[j]*v0[j] + v1[j]*v1[j] + v2[j]*v2[j] + v3[j]*v3[j];
    ss += __shfl_xor(ss, 1); ss += __shfl_xor(ss, 2);
    ss += __shfl_xor(ss, 4); ss += __shfl_xor(ss, 8);
    float rn = 1.0f / fmaxf(sqrtf(ss), 1e-12f);
    v0 *= rn; v1 *= rn; v2 *= rn; v3 *= rn;
    u32 sw = (u32)((i & 7) << 4);
    *(i32x4*)(lds + 32768 + (((u32)i * 512 + (u32)(part * 16) * 2) ^ sw)) = cvt8(v0, v1);
    *(i32x4*)(lds + 32768 + (((u32)i * 512 + (u32)(part * 16) * 2 + 16) ^ sw)) = cvt8(v2, v3);
  }
  __syncthreads();
  {
    f32x4 acc[4] = {};
    for (int kt = 0; kt < 8; ++kt) {
      u32 r0 = (u32)r15;
      i32x4 a0 = *(const i32x4*)(lds + 32768 + ((r0 * 512 + (u32)kt * 64 + (u32)g * 16) ^ ((r0 & 7) << 4)));
      #pragma unroll
      for (int n4 = 0; n4 < 4; ++n4) {
        int nt = w * 4 + n4;
        i32x4 b = *(const i32x4*)(wlatf + (((size_t)(kt * 16 + nt) * 64 + lane) << 3));
        acc[n4] = MFMA(a0, b, acc[n4]);
      }
    }
    #pragma unroll
    for (int n4 = 0; n4 < 4; ++n4) {
      int col = (w * 4 + n4) * 16 + r15;
      float bv = blat[col];
      #pragma unroll
      for (int j = 0; j < 4; ++j)
        zbuf[(g * 4 + j) * 256 + col] = acc[n4][j] + bv;
    }
  }
  __syncthreads();
  {
    int i = tid >> 4, part = tid & 15;
    float* zr = zbuf + i * 256 + part * 16;
    float* orow = zz + (size_t)(d0 + i) * 256 + part * 16;
    #pragma unroll
    for (int c = 0; c < 16; c += 4) *(f32x4*)(orow + c) = *(const f32x4*)(zr + c);
  }
  {
    int c = tid; float s1 = 0.0f, s2 = 0.0f;
    #pragma unroll
    for (int r = 0; r < 16; ++r) { float v = zbuf[r * 256 + c]; s1 += v; s2 += v * v; }
    atomicAdd(&statl[c], s1); atomicAdd(&statl[256 + c], s2);
  }
}

// ---------------- K7: out = bnl(zz) (kfin folded in) ----------------
__global__ void k7_out(const float* __restrict__ zz, const float* __restrict__ statl,
                       const float* __restrict__ gg, const float* __restrict__ bb,
                       float* __restrict__ out) {
  int idx = blockIdx.x * 256 + threadIdx.x;
  int e0 = idx * 4;
  int c = e0 & 255;
  const float inv_n = 1.0f / (float)CN2;
  f32x4 s1 = *(const f32x4*)(statl + c);
  f32x4 s2 = *(const f32x4*)(statl + 256 + c);
  f32x4 gv = *(const f32x4*)(gg + c);
  f32x4 bv = *(const f32x4*)(bb + c);
  f32x4 v = *(const f32x4*)(zz + e0);
  f32x4 o;
  #pragma unroll
  for (int j = 0; j < 4; ++j) {
    float mu = s1[j] * inv_n;
    float var = s2[j] * inv_n - mu * mu;
    float sc = gv[j] / sqrtf(var + 1e-5f);
    o[j] = v[j] * sc + (bv[j] - mu * sc);
  }
  *(f32x4*)(out + e0) = o;
}

extern "C" void kernel_launch(void* const* d_in, const int* in_sizes, int n_in,
                              void* d_out, int out_size, void* d_ws, size_t ws_size,
                              hipStream_t stream) {
  const float* x     = (const float*)d_in[0];
  const int*   es0   = (const int*)d_in[1];
  const int*   es1   = (const int*)d_in[3];
  const float* Wp0   = (const float*)d_in[5];
  const float* bp0   = (const float*)d_in[6];
  const float* Ws0   = (const float*)d_in[7];
  const float* Wn0   = (const float*)d_in[8];
  const float* b0v   = (const float*)d_in[9];
  const float* Wp1   = (const float*)d_in[10];
  const float* bp1   = (const float*)d_in[11];
  const float* Ws1   = (const float*)d_in[12];
  const float* Wn1   = (const float*)d_in[13];
  const float* b1v   = (const float*)d_in[14];
  const float* gbn0  = (const float*)d_in[15];
  const float* bebn0 = (const float*)d_in[16];
  const float* Wh    = (const float*)d_in[17];
  const float* bh    = (const float*)d_in[18];
  const float* gbnh  = (const float*)d_in[19];
  const float* bebnh = (const float*)d_in[20];
  const float* Wlat  = (const float*)d_in[21];
  const float* blat  = (const float*)d_in[22];
  const float* gbnl  = (const float*)d_in[23];
  const float* bebnl = (const float*)d_in[24];

  char* ws = (char*)d_ws;
  u16* h0    = (u16*)(ws + H0_OFF);
  u16* tban  = (u16*)(ws + T_OFF);
  u16* m1    = (u16*)(ws + H0_OFF);   // reuse: h0 dead after hidden GEMM
  u16* h2    = (u16*)(ws + H2_OFF);
  float* zz  = (float*)(ws + ZZ_OFF);
  u16* wp0f  = (u16*)(ws + WP0F_OFF);
  u16* wc0f  = (u16*)(ws + WC0F_OFF);
  u16* whf   = (u16*)(ws + WHF_OFF);
  u16* wp1f  = (u16*)(ws + WP1F_OFF);
  u16* wc1f  = (u16*)(ws + WC1F_OFF);
  u16* wlatf = (u16*)(ws + WLATF_OFF);
  float* stat = (float*)(ws + STAT_OFF);

  kprep<<<128, 256, 0, stream>>>(Wp0, Ws0, Wn0, Wh, Wp1, Ws1, Wn1, Wlat,
                                 wp0f, wc0f, whf, wp1f, wc1f, wlatf, stat);
  k1_layer0<<<CN1 / 32, 256, 0, stream>>>(x, es0, wp0f, wc0f, bp0, b0v, h0, stat);
  gemm64<false, true, false><<<CN1 / 64, 256, 0, stream>>>(
      h0, stat, 1.0f / CN1, gbn0, bebn0, whf, bh, tban, stat + 512, nullptr);
  gemm64<true, false, true><<<CN1 / 64, 256, 0, stream>>>(
      tban, stat + 512, 1.0f / CN1, gbnh, bebnh, wp1f, bp1, m1, nullptr, h2);
  k6_layer1<<<CN2 / 16, 256, 0, stream>>>(es1, m1, h2, wc1f, wlatf, b1v, blat, zz,
                                          stat + 1024);
  k7_out<<<out_size / 1024, 256, 0, stream>>>(zz, stat + 1024, gbnl, bebnl,
                                              (float*)d_out);
  (void)in_sizes; (void)n_in; (void)ws_size;
}